// Round 1
// baseline (1811.011 us; speedup 1.0000x reference)
//
#include <hip/hip_runtime.h>
#include <hip/hip_bf16.h>

// Problem constants (FujiRoutedExperts): E=32, D=1024, I=512, T=4096, K=8
#define E_   32
#define D_   1024
#define I_   512
#define T_   4096
#define KTOP 8
#define TK   (T_*KTOP)       // 32768 (token, slot) assignments

// GEMM tiling
#define BM 64
#define BN 64
#define BK 16
#define MAX_TILES (TK/BM + E_)   // 544 worst-case row-tiles across all experts

// Workspace layout (int index into ws):
//  w[0]        : idx-is-int64 flag
//  w[32..63]   : per-expert counts
//  w[64..95]   : per-expert scatter cursors
//  w[96..128]  : per-expert segment offsets (exclusive scan, offsets[32]=TK)
//  w[129]      : number of row-tiles
//  byte 1024   : int2 tiles[MAX_TILES]  (expert, row_start)
//  byte 8192   : int   tok[TK]          (token id per gathered entry)
//  byte 139264 : float wt[TK]           (routing weight per gathered entry)
//  byte 524288 : H [TK][I_]             (SwiGLU output, fp32 or bf16 fallback)
#define TILES_OFF 1024
#define TOK_OFF   8192
#define WT_OFF    139264
#define H_OFF     524288

// ---------------------------------------------------------------- routing ---

// top_k_indices is jnp.int64 in the reference, but JAX without x64 silently
// makes it int32. Detect on-device: int64 values 0..31 little-endian have all
// high (odd int32) words == 0; random int32 indices essentially never do.
__global__ void detect_idx64_kernel(const int* __restrict__ idx32, int* w) {
    if (threadIdx.x == 0 && blockIdx.x == 0) {
        int all0 = 1;
        for (int i = 0; i < 256; ++i)
            if (idx32[2*i + 1] != 0) { all0 = 0; break; }
        w[0] = all0;
    }
}

__global__ void count_kernel(const int* __restrict__ idx32, int* w) {
    int i = blockIdx.x * blockDim.x + threadIdx.x;
    if (i >= TK) return;
    int e = w[0] ? idx32[2*i] : idx32[i];
    atomicAdd(&w[32 + e], 1);
}

__global__ void scan_kernel(int* w) {
    if (threadIdx.x != 0 || blockIdx.x != 0) return;
    int off = 0;
    for (int e = 0; e < E_; ++e) { w[96 + e] = off; off += w[32 + e]; }
    w[96 + E_] = off;
    int2* tiles = (int2*)((char*)w + TILES_OFF);
    int nt = 0;
    for (int e = 0; e < E_; ++e)
        for (int rs = w[96 + e]; rs < w[96 + e + 1]; rs += BM)
            tiles[nt++] = make_int2(e, rs);
    w[129] = nt;
}

__global__ void scatter_kernel(const int* __restrict__ idx32,
                               const float* __restrict__ wts, int* w) {
    int i = blockIdx.x * blockDim.x + threadIdx.x;
    if (i >= TK) return;
    int e = w[0] ? idx32[2*i] : idx32[i];
    int p = atomicAdd(&w[64 + e], 1);
    int pos = w[96 + e] + p;
    ((int*)  ((char*)w + TOK_OFF))[pos] = i / KTOP;
    ((float*)((char*)w + WT_OFF))[pos]  = wts[i];
}

// ------------------------------------------------------------- GEMM cores ---

__device__ inline void load4f(const float* p, float& x, float& y, float& z, float& u) {
    float4 v = *(const float4*)p; x = v.x; y = v.y; z = v.z; u = v.w;
}
__device__ inline void load4f(const __hip_bfloat16* p, float& x, float& y, float& z, float& u) {
    x = __bfloat162float(p[0]); y = __bfloat162float(p[1]);
    z = __bfloat162float(p[2]); u = __bfloat162float(p[3]);
}

// GEMM1 + SwiGLU: for each gathered entry row, H[row, n] =
//   silu(x . Wgate[n]) * (x . Wup[n]),  n in [n0, n0+BN), K-dim = D_.
// Each block computes BOTH the gate tile (rows n0..) and the matching up tile
// (rows I_+n0..) so SwiGLU fuses in-register. gridDim.x = I_/BN = 8.
template <typename HT>
__global__ __launch_bounds__(256) void gemm1_kernel(
    const float* __restrict__ hidden, const float* __restrict__ gup,
    const int* __restrict__ w, HT* __restrict__ H)
{
    int nt = w[129];
    if ((int)blockIdx.y >= nt) return;
    int2 tl = ((const int2*)((const char*)w + TILES_OFF))[blockIdx.y];
    const int e = tl.x, rs = tl.y;
    int rows = w[96 + e + 1] - rs; if (rows > BM) rows = BM;
    const int* tok = (const int*)((const char*)w + TOK_OFF);

    __shared__ float As[BK][BM + 4];
    __shared__ float Bg[BK][BN + 4];
    __shared__ float Bu[BK][BN + 4];
    __shared__ int   tokS[BM];

    const int tid = threadIdx.x;
    if (tid < BM) tokS[tid] = tok[rs + min(tid, rows - 1)];
    __syncthreads();

    const int n0 = blockIdx.x * BN;
    const int lr = tid >> 2;          // 0..63: row this thread loads
    const int lk = (tid & 3) * 4;     // 0,4,8,12: k-offset (float4)
    const int ty = tid >> 4, tx = tid & 15;

    const float* gb   = gup + (size_t)e * (2 * I_) * (size_t)D_;
    const float* arow = hidden + (size_t)tokS[lr] * D_ + lk;
    const float* grow = gb + (size_t)(n0 + lr) * D_ + lk;
    const float* urow = gb + (size_t)(I_ + n0 + lr) * D_ + lk;

    float cg[4][4] = {{0.f}}, cu[4][4] = {{0.f}};

    for (int k0 = 0; k0 < D_; k0 += BK) {
        float4 a  = *(const float4*)(arow + k0);
        float4 g4 = *(const float4*)(grow + k0);
        float4 u4 = *(const float4*)(urow + k0);
        __syncthreads();
        As[lk+0][lr]=a.x;  As[lk+1][lr]=a.y;  As[lk+2][lr]=a.z;  As[lk+3][lr]=a.w;
        Bg[lk+0][lr]=g4.x; Bg[lk+1][lr]=g4.y; Bg[lk+2][lr]=g4.z; Bg[lk+3][lr]=g4.w;
        Bu[lk+0][lr]=u4.x; Bu[lk+1][lr]=u4.y; Bu[lk+2][lr]=u4.z; Bu[lk+3][lr]=u4.w;
        __syncthreads();
#pragma unroll
        for (int kk = 0; kk < BK; ++kk) {
            float4 av = *(const float4*)&As[kk][ty * 4];
            float4 gv = *(const float4*)&Bg[kk][tx * 4];
            float4 uv = *(const float4*)&Bu[kk][tx * 4];
            float aa[4] = {av.x, av.y, av.z, av.w};
            float gg[4] = {gv.x, gv.y, gv.z, gv.w};
            float uu[4] = {uv.x, uv.y, uv.z, uv.w};
#pragma unroll
            for (int i = 0; i < 4; ++i)
#pragma unroll
                for (int j = 0; j < 4; ++j) {
                    cg[i][j] += aa[i] * gg[j];
                    cu[i][j] += aa[i] * uu[j];
                }
        }
    }

#pragma unroll
    for (int i = 0; i < 4; ++i) {
        int m = ty * 4 + i;
        if (m < rows) {
            HT* hrow = H + (size_t)(rs + m) * I_ + n0 + tx * 4;
#pragma unroll
            for (int j = 0; j < 4; ++j) {
                float g = cg[i][j];
                float s = g / (1.f + expf(-g));   // silu
                hrow[j] = (HT)(s * cu[i][j]);
            }
        }
    }
}

// GEMM2 + combine: out[tok, n] += wt * (H[row] . Wd[n]), K-dim = I_.
// gridDim.x = D_/BN = 16. Cross-expert accumulation via fp32 atomicAdd.
template <typename HT>
__global__ __launch_bounds__(256) void gemm2_kernel(
    const HT* __restrict__ H, const float* __restrict__ down,
    const int* __restrict__ w, float* __restrict__ out)
{
    int nt = w[129];
    if ((int)blockIdx.y >= nt) return;
    int2 tl = ((const int2*)((const char*)w + TILES_OFF))[blockIdx.y];
    const int e = tl.x, rs = tl.y;
    int rows = w[96 + e + 1] - rs; if (rows > BM) rows = BM;
    const int*   tok = (const int*)  ((const char*)w + TOK_OFF);
    const float* wts = (const float*)((const char*)w + WT_OFF);

    __shared__ float As[BK][BM + 4];
    __shared__ float Bs[BK][BN + 4];
    __shared__ int   tokS[BM];
    __shared__ float wtS[BM];

    const int tid = threadIdx.x;
    if (tid < BM) {
        tokS[tid] = tok[rs + min(tid, rows - 1)];
        wtS[tid]  = (tid < rows) ? wts[rs + tid] : 0.f;
    }
    __syncthreads();

    const int n0 = blockIdx.x * BN;
    const int lr = tid >> 2;
    const int lk = (tid & 3) * 4;
    const int ty = tid >> 4, tx = tid & 15;

    const HT*    ar = H + (size_t)(rs + min(lr, rows - 1)) * I_ + lk;
    const float* br = down + (size_t)e * D_ * I_ + (size_t)(n0 + lr) * I_ + lk;

    float c[4][4] = {{0.f}};

    for (int k0 = 0; k0 < I_; k0 += BK) {
        float a0, a1, a2, a3;
        load4f(ar + k0, a0, a1, a2, a3);
        float4 b = *(const float4*)(br + k0);
        __syncthreads();
        As[lk+0][lr]=a0;  As[lk+1][lr]=a1;  As[lk+2][lr]=a2;  As[lk+3][lr]=a3;
        Bs[lk+0][lr]=b.x; Bs[lk+1][lr]=b.y; Bs[lk+2][lr]=b.z; Bs[lk+3][lr]=b.w;
        __syncthreads();
#pragma unroll
        for (int kk = 0; kk < BK; ++kk) {
            float4 av = *(const float4*)&As[kk][ty * 4];
            float4 bv = *(const float4*)&Bs[kk][tx * 4];
            float aa[4] = {av.x, av.y, av.z, av.w};
            float bb[4] = {bv.x, bv.y, bv.z, bv.w};
#pragma unroll
            for (int i = 0; i < 4; ++i)
#pragma unroll
                for (int j = 0; j < 4; ++j)
                    c[i][j] += aa[i] * bb[j];
        }
    }

#pragma unroll
    for (int i = 0; i < 4; ++i) {
        int m = ty * 4 + i;
        if (m < rows) {
            float wt = wtS[m];
            float* orow = out + (size_t)tokS[m] * D_ + n0 + tx * 4;
#pragma unroll
            for (int j = 0; j < 4; ++j)
                atomicAdd(&orow[j], wt * c[i][j]);
        }
    }
}

// ------------------------------------------------------------------ launch --

extern "C" void kernel_launch(void* const* d_in, const int* in_sizes, int n_in,
                              void* d_out, int out_size, void* d_ws, size_t ws_size,
                              hipStream_t stream)
{
    const float* hidden = (const float*)d_in[0];
    const int*   idx    = (const int*)  d_in[1];   // int32 or int64 (detected)
    const float* wts    = (const float*)d_in[2];
    const float* gup    = (const float*)d_in[3];
    const float* down   = (const float*)d_in[4];
    float* out = (float*)d_out;
    int*   w   = (int*)d_ws;

    // ws header + output are re-poisoned 0xAA before every timed launch.
    hipMemsetAsync(d_ws, 0, 8192, stream);
    hipMemsetAsync(d_out, 0, (size_t)T_ * D_ * sizeof(float), stream);

    detect_idx64_kernel<<<1, 64, 0, stream>>>(idx, w);
    count_kernel<<<(TK + 255) / 256, 256, 0, stream>>>(idx, w);
    scan_kernel<<<1, 32, 0, stream>>>(w);
    scatter_kernel<<<(TK + 255) / 256, 256, 0, stream>>>(idx, wts, w);

    const size_t h_f32_bytes = (size_t)TK * I_ * sizeof(float);
    bool h_fp32 = ws_size >= H_OFF + h_f32_bytes;  // host-side, stable per call

    dim3 g1(I_ / BN, MAX_TILES), g2(D_ / BN, MAX_TILES);
    if (h_fp32) {
        float* H = (float*)((char*)d_ws + H_OFF);
        gemm1_kernel<float><<<g1, 256, 0, stream>>>(hidden, gup, w, H);
        gemm2_kernel<float><<<g2, 256, 0, stream>>>(H, down, w, out);
    } else {
        __hip_bfloat16* H = (__hip_bfloat16*)((char*)d_ws + H_OFF);
        gemm1_kernel<__hip_bfloat16><<<g1, 256, 0, stream>>>(hidden, gup, w, H);
        gemm2_kernel<__hip_bfloat16><<<g2, 256, 0, stream>>>(H, down, w, out);
    }
}

// Round 2
// 732.991 us; speedup vs baseline: 2.4707x; 2.4707x over previous
//
#include <hip/hip_runtime.h>
#include <hip/hip_bf16.h>

// FujiRoutedExperts: E=32, D=1024, I=512, T=4096, K=8 (all fp32 in/out)
#define E_   32
#define D_   1024
#define I_   512
#define T_   4096
#define KTOP 8
#define TK   (T_*KTOP)          // 32768 gathered (token, slot) rows

// MFMA GEMM tiling: 128x128 tile, BK=32 (one 16x16x32 MFMA K-depth)
#define BM   128
#define BKK  32
#define MAXT (TK/BM + E_)       // 288 worst-case row-tiles

// Workspace layout:
//  w[0]      idx-is-int64 flag
//  w[32..63] per-expert counts | w[64..95] scatter cursors
//  w[96..128] segment offsets (off[32]=TK) | w[129] tile count
//  byte 1024   int2 tiles[MAXT]
//  byte 8192   int   tok[TK]
//  byte 139264 float wt[TK]
//  byte 524288 bf16  H[TK][I_]   (32 MB; proven to fit last round)
#define TILES_OFF 1024
#define TOK_OFF   8192
#define WT_OFF    139264
#define H_OFF     524288

typedef __attribute__((ext_vector_type(8))) short short8v;   // 8 bf16 = 4 VGPR
typedef __attribute__((ext_vector_type(4))) float f32x4;     // MFMA acc

__device__ inline unsigned short f2bf(float x) {             // fp32 -> bf16 RNE
    union { float f; unsigned u; } v; v.f = x;
    return (unsigned short)((v.u + 0x7fff + ((v.u >> 16) & 1)) >> 16);
}
__device__ inline short8v pack8(float4 a, float4 b) {
    short8v r;
    r[0]=(short)f2bf(a.x); r[1]=(short)f2bf(a.y); r[2]=(short)f2bf(a.z); r[3]=(short)f2bf(a.w);
    r[4]=(short)f2bf(b.x); r[5]=(short)f2bf(b.y); r[6]=(short)f2bf(b.z); r[7]=(short)f2bf(b.w);
    return r;
}

// ---------------------------------------------------------------- routing ---

// int64 indices little-endian 0..31 have all odd int32 words zero.
__global__ void detect_idx64_kernel(const int* __restrict__ idx32, int* w) {
    if (threadIdx.x == 0 && blockIdx.x == 0) {
        int all0 = 1;
        for (int i = 0; i < 256; ++i)
            if (idx32[2*i + 1] != 0) { all0 = 0; break; }
        w[0] = all0;
    }
}

__global__ void count_kernel(const int* __restrict__ idx32, int* w) {
    int i = blockIdx.x * blockDim.x + threadIdx.x;
    if (i >= TK) return;
    int e = w[0] ? idx32[2*i] : idx32[i];
    atomicAdd(&w[32 + e], 1);
}

__global__ void scan_kernel(int* w) {
    if (threadIdx.x != 0 || blockIdx.x != 0) return;
    int off = 0;
    for (int e = 0; e < E_; ++e) { w[96 + e] = off; off += w[32 + e]; }
    w[96 + E_] = off;
    int2* tiles = (int2*)((char*)w + TILES_OFF);
    int nt = 0;
    for (int e = 0; e < E_; ++e)
        for (int rs = w[96 + e]; rs < w[96 + e + 1]; rs += BM)
            tiles[nt++] = make_int2(e, rs);
    w[129] = nt;
}

__global__ void scatter_kernel(const int* __restrict__ idx32,
                               const float* __restrict__ wts, int* w) {
    int i = blockIdx.x * blockDim.x + threadIdx.x;
    if (i >= TK) return;
    int e = w[0] ? idx32[2*i] : idx32[i];
    int p = atomicAdd(&w[64 + e], 1);
    int pos = w[96 + e] + p;
    ((int*)  ((char*)w + TOK_OFF))[pos] = i / KTOP;
    ((float*)((char*)w + WT_OFF))[pos]  = wts[i];
}

// --------------------------------------------------------------- GEMM1 ------
// H[row, n] = silu(x.Wgate[n]) * (x.Wup[n]); M=TK (gathered), N=I_, K=D_.
// Block: 128 rows x 64 SwiGLU cols (= 128 B-rows: 64 gate + 64 up stacked).
// 4 waves, each 32 rows x 128 cols = 2x8 frags of 16x16x32 bf16 MFMA.
__global__ __launch_bounds__(256) void gemm1_mfma(
    const float* __restrict__ hidden, const float* __restrict__ gup,
    const int* __restrict__ w, unsigned short* __restrict__ H)
{
    if ((int)blockIdx.y >= w[129]) return;
    int2 tl = ((const int2*)((const char*)w + TILES_OFF))[blockIdx.y];
    const int e = tl.x, rs = tl.y;
    const int rows = min(w[96 + e + 1] - rs, BM);
    const int* tok = (const int*)((const char*)w + TOK_OFF);

    __shared__ short As[BM * BKK];
    __shared__ short Bs[BM * BKK];
    __shared__ int tokS[BM];

    const int tid = threadIdx.x;
    if (tid < BM) tokS[tid] = tok[rs + min(tid, rows - 1)];
    __syncthreads();

    const int n0 = blockIdx.x * 64;                 // SwiGLU col block
    const float* gb = gup + (size_t)e * (2 * I_) * D_;

    // staging: thread -> (row = tid>>2, kgroup = tid&3 of 8 floats); 2 rows each
    const int crow = tid >> 2, ckg = tid & 3;
    const float* aptr0 = hidden + (size_t)tokS[crow]      * D_ + ckg * 8;
    const float* aptr1 = hidden + (size_t)tokS[crow + 64] * D_ + ckg * 8;
    const float* bptr0 = gb + (size_t)(n0 + crow)      * D_ + ckg * 8;  // gate
    const float* bptr1 = gb + (size_t)(I_ + n0 + crow) * D_ + ckg * 8;  // up
    short8v* wA0 = (short8v*)&As[crow * BKK + ckg * 8];
    short8v* wA1 = (short8v*)&As[(crow + 64) * BKK + ckg * 8];
    short8v* wB0 = (short8v*)&Bs[crow * BKK + ckg * 8];
    short8v* wB1 = (short8v*)&Bs[(crow + 64) * BKK + ckg * 8];

    const int wid = tid >> 6, lane = tid & 63;
    const int l16 = lane & 15, lk = (lane >> 4) * 8;
    const int aoff = (wid * 32 + l16) * BKK + lk;   // A frag, row-block 0
    const int boff = l16 * BKK + lk;                // B^T frag, col-block 0

    f32x4 acc[2][8];
#pragma unroll
    for (int i = 0; i < 2; ++i)
#pragma unroll
        for (int j = 0; j < 8; ++j) acc[i][j] = (f32x4){0.f, 0.f, 0.f, 0.f};

    float4 ra0a, ra0b, ra1a, ra1b, rb0a, rb0b, rb1a, rb1b;
#define LOADREGS1(K0) { \
    ra0a = *(const float4*)(aptr0 + (K0)); ra0b = *(const float4*)(aptr0 + (K0) + 4); \
    ra1a = *(const float4*)(aptr1 + (K0)); ra1b = *(const float4*)(aptr1 + (K0) + 4); \
    rb0a = *(const float4*)(bptr0 + (K0)); rb0b = *(const float4*)(bptr0 + (K0) + 4); \
    rb1a = *(const float4*)(bptr1 + (K0)); rb1b = *(const float4*)(bptr1 + (K0) + 4); }

    LOADREGS1(0);
    for (int k0 = 0; k0 < D_; k0 += BKK) {
        __syncthreads();
        *wA0 = pack8(ra0a, ra0b);
        *wA1 = pack8(ra1a, ra1b);
        *wB0 = pack8(rb0a, rb0b);
        *wB1 = pack8(rb1a, rb1b);
        __syncthreads();
        if (k0 + BKK < D_) LOADREGS1(k0 + BKK);
        short8v a0 = *(const short8v*)&As[aoff];
        short8v a1 = *(const short8v*)&As[aoff + 16 * BKK];
#pragma unroll
        for (int j = 0; j < 8; ++j) {
            short8v b = *(const short8v*)&Bs[boff + j * 16 * BKK];
            acc[0][j] = __builtin_amdgcn_mfma_f32_16x16x32_bf16(a0, b, acc[0][j], 0, 0, 0);
            acc[1][j] = __builtin_amdgcn_mfma_f32_16x16x32_bf16(a1, b, acc[1][j], 0, 0, 0);
        }
    }

    // SwiGLU epilogue: frag j (cols j*16..) is gate, j+4 is up, same lanes/rows.
    const int r0 = (lane >> 4) * 4;
#pragma unroll
    for (int mr = 0; mr < 2; ++mr)
#pragma unroll
        for (int j = 0; j < 4; ++j)
#pragma unroll
            for (int r = 0; r < 4; ++r) {
                int m = wid * 32 + mr * 16 + r0 + r;
                if (m < rows) {
                    float g = acc[mr][j][r], u = acc[mr][j + 4][r];
                    float s = g / (1.f + __expf(-g));
                    H[(size_t)(rs + m) * I_ + n0 + j * 16 + l16] = f2bf(s * u);
                }
            }
}

// --------------------------------------------------------------- GEMM2 ------
// out[tok,n] += wt * (H[row].Wd[n]); M=TK, N=D_, K=I_. Same tile structure.
__global__ __launch_bounds__(256) void gemm2_mfma(
    const unsigned short* __restrict__ H, const float* __restrict__ down,
    const int* __restrict__ w, float* __restrict__ out)
{
    if ((int)blockIdx.y >= w[129]) return;
    int2 tl = ((const int2*)((const char*)w + TILES_OFF))[blockIdx.y];
    const int e = tl.x, rs = tl.y;
    const int rows = min(w[96 + e + 1] - rs, BM);
    const int*   tok = (const int*)  ((const char*)w + TOK_OFF);
    const float* wts = (const float*)((const char*)w + WT_OFF);

    __shared__ short As[BM * BKK];
    __shared__ short Bs[BM * BKK];
    __shared__ int   tokS[BM];
    __shared__ float wtS[BM];

    const int tid = threadIdx.x;
    if (tid < BM) {
        tokS[tid] = tok[rs + min(tid, rows - 1)];
        wtS[tid]  = (tid < rows) ? wts[rs + tid] : 0.f;
    }
    __syncthreads();

    const int n0 = blockIdx.x * 128;
    const float* db = down + (size_t)e * D_ * I_;

    const int crow = tid >> 2, ckg = tid & 3;
    // A = H (already bf16): straight 16B copies; clamp final-tile overrun.
    const short* ha0 = (const short*)H + (size_t)min(rs + crow,      TK - 1) * I_ + ckg * 8;
    const short* ha1 = (const short*)H + (size_t)min(rs + crow + 64, TK - 1) * I_ + ckg * 8;
    const float* bptr0 = db + (size_t)(n0 + crow)      * I_ + ckg * 8;
    const float* bptr1 = db + (size_t)(n0 + crow + 64) * I_ + ckg * 8;
    short8v* wA0 = (short8v*)&As[crow * BKK + ckg * 8];
    short8v* wA1 = (short8v*)&As[(crow + 64) * BKK + ckg * 8];
    short8v* wB0 = (short8v*)&Bs[crow * BKK + ckg * 8];
    short8v* wB1 = (short8v*)&Bs[(crow + 64) * BKK + ckg * 8];

    const int wid = tid >> 6, lane = tid & 63;
    const int l16 = lane & 15, lk = (lane >> 4) * 8;
    const int aoff = (wid * 32 + l16) * BKK + lk;
    const int boff = l16 * BKK + lk;

    f32x4 acc[2][8];
#pragma unroll
    for (int i = 0; i < 2; ++i)
#pragma unroll
        for (int j = 0; j < 8; ++j) acc[i][j] = (f32x4){0.f, 0.f, 0.f, 0.f};

    short8v raa, rab;
    float4 rb0a, rb0b, rb1a, rb1b;
#define LOADREGS2(K0) { \
    raa = *(const short8v*)(ha0 + (K0)); rab = *(const short8v*)(ha1 + (K0)); \
    rb0a = *(const float4*)(bptr0 + (K0)); rb0b = *(const float4*)(bptr0 + (K0) + 4); \
    rb1a = *(const float4*)(bptr1 + (K0)); rb1b = *(const float4*)(bptr1 + (K0) + 4); }

    LOADREGS2(0);
    for (int k0 = 0; k0 < I_; k0 += BKK) {
        __syncthreads();
        *wA0 = raa;
        *wA1 = rab;
        *wB0 = pack8(rb0a, rb0b);
        *wB1 = pack8(rb1a, rb1b);
        __syncthreads();
        if (k0 + BKK < I_) LOADREGS2(k0 + BKK);
        short8v a0 = *(const short8v*)&As[aoff];
        short8v a1 = *(const short8v*)&As[aoff + 16 * BKK];
#pragma unroll
        for (int j = 0; j < 8; ++j) {
            short8v b = *(const short8v*)&Bs[boff + j * 16 * BKK];
            acc[0][j] = __builtin_amdgcn_mfma_f32_16x16x32_bf16(a0, b, acc[0][j], 0, 0, 0);
            acc[1][j] = __builtin_amdgcn_mfma_f32_16x16x32_bf16(a1, b, acc[1][j], 0, 0, 0);
        }
    }

    const int r0 = (lane >> 4) * 4;
#pragma unroll
    for (int mr = 0; mr < 2; ++mr)
#pragma unroll
        for (int j = 0; j < 8; ++j)
#pragma unroll
            for (int r = 0; r < 4; ++r) {
                int m = wid * 32 + mr * 16 + r0 + r;
                if (m < rows)
                    atomicAdd(&out[(size_t)tokS[m] * D_ + n0 + j * 16 + l16],
                              wtS[m] * acc[mr][j][r]);
            }
}

// ------------------------------------------------------------------ launch --

extern "C" void kernel_launch(void* const* d_in, const int* in_sizes, int n_in,
                              void* d_out, int out_size, void* d_ws, size_t ws_size,
                              hipStream_t stream)
{
    const float* hidden = (const float*)d_in[0];
    const int*   idx    = (const int*)  d_in[1];   // int32 or int64 (detected)
    const float* wts    = (const float*)d_in[2];
    const float* gup    = (const float*)d_in[3];
    const float* down   = (const float*)d_in[4];
    float* out = (float*)d_out;
    int*   w   = (int*)d_ws;

    hipMemsetAsync(d_ws, 0, 8192, stream);                              // header+tiles
    hipMemsetAsync(d_out, 0, (size_t)T_ * D_ * sizeof(float), stream);  // atomic target

    detect_idx64_kernel<<<1, 64, 0, stream>>>(idx, w);
    count_kernel<<<(TK + 255) / 256, 256, 0, stream>>>(idx, w);
    scan_kernel<<<1, 32, 0, stream>>>(w);
    scatter_kernel<<<(TK + 255) / 256, 256, 0, stream>>>(idx, wts, w);

    unsigned short* H = (unsigned short*)((char*)d_ws + H_OFF);
    dim3 g1(I_ / 64, MAXT), g2(D_ / 128, MAXT);
    gemm1_mfma<<<g1, 256, 0, stream>>>(hidden, gup, w, H);
    gemm2_mfma<<<g2, 256, 0, stream>>>(H, down, w, out);
}

// Round 3
// 687.412 us; speedup vs baseline: 2.6345x; 1.0663x over previous
//
#include <hip/hip_runtime.h>
#include <hip/hip_bf16.h>

// FujiRoutedExperts: E=32, D=1024, I=512, T=4096, K=8 (all fp32 in/out)
#define E_   32
#define D_   1024
#define I_   512
#define T_   4096
#define KTOP 8
#define TK   (T_*KTOP)          // 32768 gathered (token, slot) rows

// MFMA GEMM tiling: 128x128 tile, BK=32 (one 16x16x32 MFMA K-depth)
#define BM   128
#define BKK  32
#define PAD  40                 // LDS row stride in shorts (80 B): bank base
                                // (20r+4s)%32 covers all banks, <=2-way = free
#define MAXT (TK/BM + E_)       // 288 worst-case row-tiles

// Workspace layout:
//  w[0]      idx-is-int64 flag
//  w[32..63] per-expert counts | w[64..95] scatter cursors
//  w[96..128] segment offsets (off[32]=TK) | w[129] tile count
//  byte 1024   int2 tiles[MAXT]
//  byte 8192   int   tok[TK]
//  byte 139264 float wt[TK]
//  byte 524288 bf16  H[TK][I_]  (32 MB, fits: bf16-H path validated in R1/R2)
#define TILES_OFF 1024
#define TOK_OFF   8192
#define WT_OFF    139264
#define H_OFF     524288

typedef __attribute__((ext_vector_type(8))) short short8v;   // 8 bf16 = 4 VGPR
typedef __attribute__((ext_vector_type(4))) float f32x4;     // MFMA acc

// fp32 -> bf16 via HIP cast: compiler pairs these into v_cvt_pk_bf16_f32
// (m240: scalar casts beat hand-rolled bit-twiddling AND inline-asm cvt_pk).
__device__ inline unsigned short f2bf(float x) {
    __hip_bfloat16 h = __float2bfloat16(x);
    union { __hip_bfloat16 h; unsigned short u; } c; c.h = h; return c.u;
}
__device__ inline short8v pack8(float4 a, float4 b) {
    short8v r;
    r[0]=(short)f2bf(a.x); r[1]=(short)f2bf(a.y); r[2]=(short)f2bf(a.z); r[3]=(short)f2bf(a.w);
    r[4]=(short)f2bf(b.x); r[5]=(short)f2bf(b.y); r[6]=(short)f2bf(b.z); r[7]=(short)f2bf(b.w);
    return r;
}

// ---------------------------------------------------------------- routing ---

// int64 indices (values 0..31, little-endian) have all odd int32 words zero.
// One wave, parallel loads, __all ballot — replaces the 256-iter serial loop.
__global__ void detect_idx64_kernel(const int* __restrict__ idx32, int* w) {
    const int lane = threadIdx.x;      // 64 threads
    int bad = 0;
#pragma unroll
    for (int j = 0; j < 4; ++j) bad |= idx32[2 * (lane + 64 * j) + 1];
    int allz = __all(bad == 0);
    if (lane == 0) w[0] = allz ? 1 : 0;
}

__global__ void count_kernel(const int* __restrict__ idx32, int* w) {
    int i = blockIdx.x * blockDim.x + threadIdx.x;
    if (i >= TK) return;
    int e = w[0] ? idx32[2*i] : idx32[i];
    atomicAdd(&w[32 + e], 1);
}

// One wave: shfl_up inclusive scans for segment offsets AND tile offsets,
// then each lane writes its own expert's tile entries (avg 8, max 256 iters).
__global__ void scan_kernel(int* w) {
    const int lane = threadIdx.x;      // 64 threads
    int cnt = (lane < E_) ? w[32 + lane] : 0;
    int x = cnt;
#pragma unroll
    for (int d = 1; d < 32; d <<= 1) {
        int v = __shfl_up(x, d, 64);
        if (lane >= d) x += v;
    }
    int excl = x - cnt;
    if (lane < E_) w[96 + lane] = excl;
    if (lane == E_ - 1) w[96 + E_] = x;

    int nt_e = (lane < E_) ? (cnt + BM - 1) / BM : 0;
    int y = nt_e;
#pragma unroll
    for (int d = 1; d < 32; d <<= 1) {
        int v = __shfl_up(y, d, 64);
        if (lane >= d) y += v;
    }
    int texcl = y - nt_e;
    if (lane == E_ - 1) w[129] = y;
    int2* tiles = (int2*)((char*)w + TILES_OFF);
    for (int i = 0; i < nt_e; ++i)
        tiles[texcl + i] = make_int2(lane, excl + i * BM);
}

__global__ void scatter_kernel(const int* __restrict__ idx32,
                               const float* __restrict__ wts, int* w) {
    int i = blockIdx.x * blockDim.x + threadIdx.x;
    if (i >= TK) return;
    int e = w[0] ? idx32[2*i] : idx32[i];
    int p = atomicAdd(&w[64 + e], 1);
    int pos = w[96 + e] + p;
    ((int*)  ((char*)w + TOK_OFF))[pos] = i / KTOP;
    ((float*)((char*)w + WT_OFF))[pos]  = wts[i];
}

// --------------------------------------------------------------- GEMM1 ------
// H[row, n] = silu(x.Wgate[n]) * (x.Wup[n]); M=TK (gathered), N=I_, K=D_.
// Block: 128 rows x 64 SwiGLU cols (= 128 B-rows: 64 gate + 64 up stacked).
// 4 waves, each 32 rows x 128 cols = 2x8 frags of 16x16x32 bf16 MFMA.
__global__ __launch_bounds__(256) void gemm1_mfma(
    const float* __restrict__ hidden, const float* __restrict__ gup,
    const int* __restrict__ w, unsigned short* __restrict__ H)
{
    if ((int)blockIdx.y >= w[129]) return;
    int2 tl = ((const int2*)((const char*)w + TILES_OFF))[blockIdx.y];
    const int e = tl.x, rs = tl.y;
    const int rows = min(w[96 + e + 1] - rs, BM);
    const int* tok = (const int*)((const char*)w + TOK_OFF);

    __shared__ short As[BM * PAD];
    __shared__ short Bs[BM * PAD];
    __shared__ int tokS[BM];

    const int tid = threadIdx.x;
    if (tid < BM) tokS[tid] = tok[rs + min(tid, rows - 1)];
    __syncthreads();

    const int n0 = blockIdx.x * 64;                 // SwiGLU col block
    const float* gb = gup + (size_t)e * (2 * I_) * D_;

    // staging: thread -> (row = tid>>2, 8-float group = tid&3); 2 rows each
    const int crow = tid >> 2, ckg = tid & 3;
    const float* aptr0 = hidden + (size_t)tokS[crow]      * D_ + ckg * 8;
    const float* aptr1 = hidden + (size_t)tokS[crow + 64] * D_ + ckg * 8;
    const float* bptr0 = gb + (size_t)(n0 + crow)      * D_ + ckg * 8;  // gate
    const float* bptr1 = gb + (size_t)(I_ + n0 + crow) * D_ + ckg * 8;  // up
    short8v* wA0 = (short8v*)&As[crow * PAD + ckg * 8];
    short8v* wA1 = (short8v*)&As[(crow + 64) * PAD + ckg * 8];
    short8v* wB0 = (short8v*)&Bs[crow * PAD + ckg * 8];
    short8v* wB1 = (short8v*)&Bs[(crow + 64) * PAD + ckg * 8];

    const int wid = tid >> 6, lane = tid & 63;
    const int l16 = lane & 15, lk = (lane >> 4) * 8;
    const int aoff = (wid * 32 + l16) * PAD + lk;   // A frag, row-block 0
    const int boff = l16 * PAD + lk;                // B^T frag, col-block 0

    f32x4 acc[2][8];
#pragma unroll
    for (int i = 0; i < 2; ++i)
#pragma unroll
        for (int j = 0; j < 8; ++j) acc[i][j] = (f32x4){0.f, 0.f, 0.f, 0.f};

    float4 ra0a, ra0b, ra1a, ra1b, rb0a, rb0b, rb1a, rb1b;
#define LOADREGS1(K0) { \
    ra0a = *(const float4*)(aptr0 + (K0)); ra0b = *(const float4*)(aptr0 + (K0) + 4); \
    ra1a = *(const float4*)(aptr1 + (K0)); ra1b = *(const float4*)(aptr1 + (K0) + 4); \
    rb0a = *(const float4*)(bptr0 + (K0)); rb0b = *(const float4*)(bptr0 + (K0) + 4); \
    rb1a = *(const float4*)(bptr1 + (K0)); rb1b = *(const float4*)(bptr1 + (K0) + 4); }

    LOADREGS1(0);
    for (int k0 = 0; k0 < D_; k0 += BKK) {
        __syncthreads();
        *wA0 = pack8(ra0a, ra0b);
        *wA1 = pack8(ra1a, ra1b);
        *wB0 = pack8(rb0a, rb0b);
        *wB1 = pack8(rb1a, rb1b);
        __syncthreads();
        if (k0 + BKK < D_) LOADREGS1(k0 + BKK);
        short8v a0 = *(const short8v*)&As[aoff];
        short8v a1 = *(const short8v*)&As[aoff + 16 * PAD];
#pragma unroll
        for (int j = 0; j < 8; ++j) {
            short8v b = *(const short8v*)&Bs[boff + j * 16 * PAD];
            acc[0][j] = __builtin_amdgcn_mfma_f32_16x16x32_bf16(a0, b, acc[0][j], 0, 0, 0);
            acc[1][j] = __builtin_amdgcn_mfma_f32_16x16x32_bf16(a1, b, acc[1][j], 0, 0, 0);
        }
    }

    // SwiGLU epilogue: frag j (cols j*16..) is gate, j+4 is up, same lanes/rows.
    const int r0 = (lane >> 4) * 4;
#pragma unroll
    for (int mr = 0; mr < 2; ++mr)
#pragma unroll
        for (int j = 0; j < 4; ++j)
#pragma unroll
            for (int r = 0; r < 4; ++r) {
                int m = wid * 32 + mr * 16 + r0 + r;
                if (m < rows) {
                    float g = acc[mr][j][r], u = acc[mr][j + 4][r];
                    float s = g / (1.f + __expf(-g));
                    H[(size_t)(rs + m) * I_ + n0 + j * 16 + l16] = f2bf(s * u);
                }
            }
}

// --------------------------------------------------------------- GEMM2 ------
// out[tok,n] += wt * (H[row].Wd[n]); M=TK, N=D_, K=I_. Same tile structure.
__global__ __launch_bounds__(256) void gemm2_mfma(
    const unsigned short* __restrict__ H, const float* __restrict__ down,
    const int* __restrict__ w, float* __restrict__ out)
{
    if ((int)blockIdx.y >= w[129]) return;
    int2 tl = ((const int2*)((const char*)w + TILES_OFF))[blockIdx.y];
    const int e = tl.x, rs = tl.y;
    const int rows = min(w[96 + e + 1] - rs, BM);
    const int*   tok = (const int*)  ((const char*)w + TOK_OFF);
    const float* wts = (const float*)((const char*)w + WT_OFF);

    __shared__ short As[BM * PAD];
    __shared__ short Bs[BM * PAD];
    __shared__ int   tokS[BM];
    __shared__ float wtS[BM];

    const int tid = threadIdx.x;
    if (tid < BM) {
        tokS[tid] = tok[rs + min(tid, rows - 1)];
        wtS[tid]  = (tid < rows) ? wts[rs + tid] : 0.f;
    }
    __syncthreads();

    const int n0 = blockIdx.x * 128;
    const float* db = down + (size_t)e * D_ * I_;

    const int crow = tid >> 2, ckg = tid & 3;
    // A = H (already bf16): straight 16B copies; clamp final-tile overrun.
    const short* ha0 = (const short*)H + (size_t)min(rs + crow,      TK - 1) * I_ + ckg * 8;
    const short* ha1 = (const short*)H + (size_t)min(rs + crow + 64, TK - 1) * I_ + ckg * 8;
    const float* bptr0 = db + (size_t)(n0 + crow)      * I_ + ckg * 8;
    const float* bptr1 = db + (size_t)(n0 + crow + 64) * I_ + ckg * 8;
    short8v* wA0 = (short8v*)&As[crow * PAD + ckg * 8];
    short8v* wA1 = (short8v*)&As[(crow + 64) * PAD + ckg * 8];
    short8v* wB0 = (short8v*)&Bs[crow * PAD + ckg * 8];
    short8v* wB1 = (short8v*)&Bs[(crow + 64) * PAD + ckg * 8];

    const int wid = tid >> 6, lane = tid & 63;
    const int l16 = lane & 15, lk = (lane >> 4) * 8;
    const int aoff = (wid * 32 + l16) * PAD + lk;
    const int boff = l16 * PAD + lk;

    f32x4 acc[2][8];
#pragma unroll
    for (int i = 0; i < 2; ++i)
#pragma unroll
        for (int j = 0; j < 8; ++j) acc[i][j] = (f32x4){0.f, 0.f, 0.f, 0.f};

    short8v raa, rab;
    float4 rb0a, rb0b, rb1a, rb1b;
#define LOADREGS2(K0) { \
    raa = *(const short8v*)(ha0 + (K0)); rab = *(const short8v*)(ha1 + (K0)); \
    rb0a = *(const float4*)(bptr0 + (K0)); rb0b = *(const float4*)(bptr0 + (K0) + 4); \
    rb1a = *(const float4*)(bptr1 + (K0)); rb1b = *(const float4*)(bptr1 + (K0) + 4); }

    LOADREGS2(0);
    for (int k0 = 0; k0 < I_; k0 += BKK) {
        __syncthreads();
        *wA0 = raa;
        *wA1 = rab;
        *wB0 = pack8(rb0a, rb0b);
        *wB1 = pack8(rb1a, rb1b);
        __syncthreads();
        if (k0 + BKK < I_) LOADREGS2(k0 + BKK);
        short8v a0 = *(const short8v*)&As[aoff];
        short8v a1 = *(const short8v*)&As[aoff + 16 * PAD];
#pragma unroll
        for (int j = 0; j < 8; ++j) {
            short8v b = *(const short8v*)&Bs[boff + j * 16 * PAD];
            acc[0][j] = __builtin_amdgcn_mfma_f32_16x16x32_bf16(a0, b, acc[0][j], 0, 0, 0);
            acc[1][j] = __builtin_amdgcn_mfma_f32_16x16x32_bf16(a1, b, acc[1][j], 0, 0, 0);
        }
    }

    const int r0 = (lane >> 4) * 4;
#pragma unroll
    for (int mr = 0; mr < 2; ++mr)
#pragma unroll
        for (int j = 0; j < 8; ++j)
#pragma unroll
            for (int r = 0; r < 4; ++r) {
                int m = wid * 32 + mr * 16 + r0 + r;
                if (m < rows)
                    atomicAdd(&out[(size_t)tokS[m] * D_ + n0 + j * 16 + l16],
                              wtS[m] * acc[mr][j][r]);
            }
}

// ------------------------------------------------------------------ launch --

extern "C" void kernel_launch(void* const* d_in, const int* in_sizes, int n_in,
                              void* d_out, int out_size, void* d_ws, size_t ws_size,
                              hipStream_t stream)
{
    const float* hidden = (const float*)d_in[0];
    const int*   idx    = (const int*)  d_in[1];   // int32 or int64 (detected)
    const float* wts    = (const float*)d_in[2];
    const float* gup    = (const float*)d_in[3];
    const float* down   = (const float*)d_in[4];
    float* out = (float*)d_out;
    int*   w   = (int*)d_ws;

    hipMemsetAsync(d_ws, 0, 8192, stream);                              // header+tiles
    hipMemsetAsync(d_out, 0, (size_t)T_ * D_ * sizeof(float), stream);  // atomic target

    detect_idx64_kernel<<<1, 64, 0, stream>>>(idx, w);
    count_kernel<<<(TK + 255) / 256, 256, 0, stream>>>(idx, w);
    scan_kernel<<<1, 64, 0, stream>>>(w);
    scatter_kernel<<<(TK + 255) / 256, 256, 0, stream>>>(idx, wts, w);

    unsigned short* H = (unsigned short*)((char*)d_ws + H_OFF);
    dim3 g1(I_ / 64, MAXT), g2(D_ / 128, MAXT);
    gemm1_mfma<<<g1, 256, 0, stream>>>(hidden, gup, w, H);
    gemm2_mfma<<<g2, 256, 0, stream>>>(H, down, w, out);
}